// Round 10
// baseline (247.068 us; speedup 1.0000x reference)
//
#include <hip/hip_runtime.h>

#define NHEADS 8
#define NB 512
#define NN 1000
#define DD 128
#define HH 128
#define SDIM 384              // D*CAT
#define NWAVE 16              // waves per block (1024 threads)

// DPP helper: x += lane-permuted x. Pure VALU, no DS pipe.
template <int CTRL>
__device__ __forceinline__ float dpp_add(float x) {
    int y = __builtin_amdgcn_update_dpp(0, __float_as_int(x), CTRL, 0xf, 0xf, true);
    return x + __int_as_float(y);
}
#define DPP_QUAD_XOR1 0xB1   // quad_perm(1,0,3,2)
#define DPP_QUAD_XOR2 0x4E   // quad_perm(2,3,0,1)
#define DPP_HALF_MIRR 0x141  // mirror within 8
#define DPP_ROW_MIRR  0x140  // mirror within 16

// Load row k (of this wave's stride-16 sequence) into named buffer P.
#define LOADR(P, kidx)                                                        \
    {                                                                         \
        const float* _np = cp + (size_t)(kidx) * (16 * DD);                   \
        P##a = *reinterpret_cast<const float4*>(_np);                         \
        P##b = *reinterpret_cast<const float4*>(_np + 4);                     \
        P##m = mp[(kidx) * 16];                                               \
    }

// Process row in buffer P. Mask is wave-uniform -> scalar branch skips the
// whole body for masked rows (~50% of rows). Loads stay unconditional.
#define BODY(P)                                                               \
    {                                                                         \
        if (__builtin_amdgcn_readfirstlane(P##m) == 0) {                      \
            const float4 C0 = P##a, C1 = P##b;                                \
            float sa = C0.x * qa0.x, sb = C0.x * qb0.x;                       \
            sa = fmaf(C0.y, qa0.y, sa); sb = fmaf(C0.y, qb0.y, sb);           \
            sa = fmaf(C0.z, qa0.z, sa); sb = fmaf(C0.z, qb0.z, sb);           \
            sa = fmaf(C0.w, qa0.w, sa); sb = fmaf(C0.w, qb0.w, sb);           \
            sa = fmaf(C1.x, qa1.x, sa); sb = fmaf(C1.x, qb1.x, sb);           \
            sa = fmaf(C1.y, qa1.y, sa); sb = fmaf(C1.y, qb1.y, sb);           \
            sa = fmaf(C1.z, qa1.z, sa); sb = fmaf(C1.z, qb1.z, sb);           \
            sa = fmaf(C1.w, qa1.w, sa); sb = fmaf(C1.w, qb1.w, sb);           \
            sa = dpp_add<DPP_QUAD_XOR1>(sa); sb = dpp_add<DPP_QUAD_XOR1>(sb); \
            sa = dpp_add<DPP_QUAD_XOR2>(sa); sb = dpp_add<DPP_QUAD_XOR2>(sb); \
            sa = dpp_add<DPP_HALF_MIRR>(sa); sb = dpp_add<DPP_HALF_MIRR>(sb); \
            sa = dpp_add<DPP_ROW_MIRR>(sa);  sb = dpp_add<DPP_ROW_MIRR>(sb);  \
            const float pa = exp2f(sa);                                       \
            const float pb = exp2f(sb);                                       \
            den0 += pa; den1 += pb;                                           \
            A0.x = fmaf(pa, C0.x, A0.x); B0.x = fmaf(pb, C0.x, B0.x);         \
            A0.y = fmaf(pa, C0.y, A0.y); B0.y = fmaf(pb, C0.y, B0.y);         \
            A0.z = fmaf(pa, C0.z, A0.z); B0.z = fmaf(pb, C0.z, B0.z);         \
            A0.w = fmaf(pa, C0.w, A0.w); B0.w = fmaf(pb, C0.w, B0.w);         \
            A1.x = fmaf(pa, C1.x, A1.x); B1.x = fmaf(pb, C1.x, B1.x);         \
            A1.y = fmaf(pa, C1.y, A1.y); B1.y = fmaf(pb, C1.y, B1.y);         \
            A1.z = fmaf(pa, C1.z, A1.z); B1.z = fmaf(pb, C1.z, B1.z);         \
            A1.w = fmaf(pa, C1.w, A1.w); B1.w = fmaf(pb, C1.w, B1.w);         \
        }                                                                     \
    }

// ---------------- single fused kernel: one block per batch ------------------
// 1024 threads = 16 waves, 2 blocks/CU (exactly 32 waves/CU, zero tail).
// Phase 1: qw[h][d] into LDS (in-block, no global traffic).
// Phase 2: wave W streams rows W, W+16, ... with the proven 3-buffer rotation;
//          4 x 16-lane groups per wave = 4 head pairs; DPP-only reduce.
// Phase 3: LDS combine + Wv/Wfc projections (octet-parallel GEMVs).
__global__ __launch_bounds__(1024, 8) void attn_one_kernel(
    const float* __restrict__ state_t,   // [B][384]
    const float* __restrict__ context,   // [B][N][128]
    const int*   __restrict__ mask,      // [B][N]
    const float* __restrict__ Wq,        // [128][384]
    const float* __restrict__ Wk,        // [128][128]
    const float* __restrict__ Wv,        // [128][128]
    const float* __restrict__ Wfc,       // [128][128]
    float* __restrict__ out)             // [B][128]
{
    const int b = blockIdx.x;
    const int t = threadIdx.x;
    const int W = t >> 6;        // wave 0..15
    const int lane = t & 63;
    const int g = lane >> 4;     // head pair 0..3
    const int j = lane & 15;     // d-slice within row

    __shared__ float s_q[HH];
    __shared__ float s_qw[NHEADS][DD];
    __shared__ float s_acc[NWAVE][NHEADS][DD];   // 64 KB
    __shared__ float s_den[NWAVE][NHEADS];
    __shared__ float s_ca[NHEADS][DD + 4];
    __shared__ float s_o2[HH];

    // ---------------- phase 1a: q[r] = state . Wq[r] ----------------
    {
        float st[6];
        #pragma unroll
        for (int c = 0; c < 6; ++c) st[c] = state_t[(size_t)b * SDIM + c * 64 + lane];
        #pragma unroll
        for (int it = 0; it < 4; ++it) {
            const int r0 = W * 8 + it * 2;
            const float* w0 = Wq + (size_t)r0 * SDIM;
            const float* w1 = w0 + SDIM;
            float p0 = 0.f, p1 = 0.f;
            #pragma unroll
            for (int c = 0; c < 6; ++c) {
                p0 = fmaf(w0[c * 64 + lane], st[c], p0);
                p1 = fmaf(w1[c * 64 + lane], st[c], p1);
            }
            #pragma unroll
            for (int off = 32; off >= 1; off >>= 1) {
                p0 += __shfl_xor(p0, off, 64);
                p1 += __shfl_xor(p1, off, 64);
            }
            if (lane == 0) { s_q[r0] = p0; s_q[r0 + 1] = p1; }
        }
    }
    __syncthreads();

    // ---------------- phase 1b: qw[h][d] (t -> h = t>>7, d = t&127) ---------
    {
        const int h = t >> 7;
        const int d = t & 127;
        const float sc = 0.0625f * 1.4426950408889634f;  // (1/hd) * log2(e)
        float a = 0.f;
        #pragma unroll
        for (int q8 = 0; q8 < 16; ++q8)
            a = fmaf(s_q[h * 16 + q8], Wk[(size_t)(h * 16 + q8) * DD + d], a);
        s_qw[h][d] = a * sc;
    }
    __syncthreads();

    // ---------------- phase 2: stream rows W, W+16, ... ----------------
    const float4 qa0 = *reinterpret_cast<const float4*>(&s_qw[2 * g][j * 8]);
    const float4 qa1 = *reinterpret_cast<const float4*>(&s_qw[2 * g][j * 8 + 4]);
    const float4 qb0 = *reinterpret_cast<const float4*>(&s_qw[2 * g + 1][j * 8]);
    const float4 qb1 = *reinterpret_cast<const float4*>(&s_qw[2 * g + 1][j * 8 + 4]);

    float4 A0 = make_float4(0.f, 0.f, 0.f, 0.f), A1 = A0;  // acc head 2g
    float4 B0 = A0, B1 = A0;                                // acc head 2g+1
    float den0 = 0.f, den1 = 0.f;

    const float* cp = context + ((size_t)b * NN + W) * DD + j * 8;
    const int*   mp = mask + (size_t)b * NN + W;

    // rows exist for k=0..61 (all waves); k=62 only for W<8 (W+992 <= 999).
    float4 p0a, p0b; int p0m;
    float4 p1a, p1b; int p1m;
    float4 p2a, p2b; int p2m;
    LOADR(p0, 0)
    LOADR(p1, 1)
    LOADR(p2, 2)

    // k = 0..56: 19 triple rounds, prefetch k+3 (max 59)
    for (int it = 0; it < 19; ++it) {
        const int k = 3 * it;
        BODY(p0) LOADR(p0, k + 3)
        BODY(p1) LOADR(p1, k + 4)
        BODY(p2) LOADR(p2, k + 5)
    }
    // peeled tail: k = 57..61
    BODY(p0) LOADR(p0, 60)
    BODY(p1) LOADR(p1, 61)
    BODY(p2)            // 59
    BODY(p0)            // 60
    BODY(p1)            // 61
    if (W < 8) {        // wave-uniform: row 62 exists only for W<8
        LOADR(p2, 62)
        BODY(p2)
    }

    // ---------------- phase 3a: per-wave partials -> LDS ----------------
    *reinterpret_cast<float4*>(&s_acc[W][2 * g][j * 8])         = A0;
    *reinterpret_cast<float4*>(&s_acc[W][2 * g][j * 8 + 4])     = A1;
    *reinterpret_cast<float4*>(&s_acc[W][2 * g + 1][j * 8])     = B0;
    *reinterpret_cast<float4*>(&s_acc[W][2 * g + 1][j * 8 + 4]) = B1;
    if (j == 0) {
        s_den[W][2 * g]     = den0;
        s_den[W][2 * g + 1] = den1;
    }
    __syncthreads();

    // ---------------- phase 3b: combine 16 waves ----------------
    {
        const int h = t >> 7;
        const int d = t & 127;
        float a = 0.f, dn = 0.f;
        #pragma unroll
        for (int sl = 0; sl < NWAVE; ++sl) {
            a  += s_acc[sl][h][d];
            dn += s_den[sl][h];
        }
        s_ca[h][d] = a / dn;
    }
    __syncthreads();

    // ---------------- phase 3c: out2[r] = ctx_attn[r/16] . Wv[r] ------------
    // thread t -> r = t>>3, octet lane jo = t&7 owning d = jo*16..jo*16+15
    {
        const int r  = t >> 3;
        const int jo = t & 7;
        const float* ca = &s_ca[r >> 4][jo * 16];
        const float* wv = Wv + (size_t)r * DD + jo * 16;
        float a = 0.f;
        #pragma unroll
        for (int k = 0; k < 16; ++k) a = fmaf(ca[k], wv[k], a);
        a = dpp_add<DPP_QUAD_XOR1>(a);
        a = dpp_add<DPP_QUAD_XOR2>(a);
        a = dpp_add<DPP_HALF_MIRR>(a);
        if (jo == 0) s_o2[r] = a;
    }
    __syncthreads();

    // ---------------- phase 3d: out[r] = out2 . Wfc[r] ----------------
    {
        const int r  = t >> 3;
        const int jo = t & 7;
        const float* o2 = &s_o2[jo * 16];
        const float* wf = Wfc + (size_t)r * DD + jo * 16;
        float a = 0.f;
        #pragma unroll
        for (int k = 0; k < 16; ++k) a = fmaf(o2[k], wf[k], a);
        a = dpp_add<DPP_QUAD_XOR1>(a);
        a = dpp_add<DPP_QUAD_XOR2>(a);
        a = dpp_add<DPP_HALF_MIRR>(a);
        if (jo == 0) out[(size_t)b * HH + r] = a;
    }
}

extern "C" void kernel_launch(void* const* d_in, const int* in_sizes, int n_in,
                              void* d_out, int out_size, void* d_ws, size_t ws_size,
                              hipStream_t stream) {
    const float* state_t = (const float*)d_in[0];
    const float* context = (const float*)d_in[1];
    const int*   mask    = (const int*)d_in[2];
    const float* Wq      = (const float*)d_in[3];
    const float* Wk      = (const float*)d_in[4];
    const float* Wv      = (const float*)d_in[5];
    const float* Wfc     = (const float*)d_in[6];
    float* out = (float*)d_out;

    attn_one_kernel<<<dim3(NB), dim3(1024), 0, stream>>>(
        state_t, context, mask, Wq, Wk, Wv, Wfc, out);
}

// Round 11
// 103.531 us; speedup vs baseline: 2.3864x; 2.3864x over previous
//
#include <hip/hip_runtime.h>

#define NHEADS 8
#define NB 512
#define NN 1000
#define DD 128
#define HH 128
#define SDIM 384              // D*CAT
#define NSPLIT 10             // blocks per batch
#define NSLOT (NSPLIT * 2)    // one partial slot per wave
#define RPW 50                // rows per wave

// DPP helper: x += lane-permuted x. Pure VALU, no DS pipe.
template <int CTRL>
__device__ __forceinline__ float dpp_add(float x) {
    int y = __builtin_amdgcn_update_dpp(0, __float_as_int(x), CTRL, 0xf, 0xf, true);
    return x + __int_as_float(y);
}
#define DPP_QUAD_XOR1 0xB1   // quad_perm(1,0,3,2)
#define DPP_QUAD_XOR2 0x4E   // quad_perm(2,3,0,1)
#define DPP_HALF_MIRR 0x141  // mirror within 8
#define DPP_ROW_MIRR  0x140  // mirror within 16

// ---------------- kernel 0: per-batch qw precompute (coalesced) -------------
__global__ __launch_bounds__(256) void qw_kernel(
    const float* __restrict__ state_t,   // [B][384]
    const float* __restrict__ Wq,        // [128][384]
    const float* __restrict__ Wk,        // [128][128]
    float* __restrict__ qw)              // [B][8][128]
{
    const int b = blockIdx.x;
    const int t = threadIdx.x;
    const int lane = t & 63;
    const int w = t >> 6;

    __shared__ float s_q[HH];

    float st[6];
    #pragma unroll
    for (int j = 0; j < 6; ++j) st[j] = state_t[(size_t)b * SDIM + j * 64 + lane];

    for (int it = 0; it < 16; ++it) {
        const int r0 = w * 32 + it * 2;
        const float* w0 = Wq + (size_t)r0 * SDIM;
        const float* w1 = w0 + SDIM;
        float p0 = 0.f, p1 = 0.f;
        #pragma unroll
        for (int j = 0; j < 6; ++j) {
            p0 = fmaf(w0[j * 64 + lane], st[j], p0);
            p1 = fmaf(w1[j * 64 + lane], st[j], p1);
        }
        #pragma unroll
        for (int off = 32; off >= 1; off >>= 1) {
            p0 += __shfl_xor(p0, off, 64);
            p1 += __shfl_xor(p1, off, 64);
        }
        if (lane == 0) { s_q[r0] = p0; s_q[r0 + 1] = p1; }
    }
    __syncthreads();

    {
        const int d  = t & 127;
        const int h0 = (t >> 7) * 4;
        const float sc = 0.0625f * 1.4426950408889634f;  // (1/hd) * log2(e)
        for (int hh = 0; hh < 4; ++hh) {
            const int h = h0 + hh;
            float a = 0.f;
            #pragma unroll
            for (int j = 0; j < 16; ++j)
                a = fmaf(s_q[h * 16 + j], Wk[(size_t)(h * 16 + j) * DD + d], a);
            qw[(size_t)b * NHEADS * DD + h * DD + d] = a * sc;
        }
    }
}

// Buffer P state: P##a,P##b = ctx row; P##m = mask of that row;
//                 P##n = mask of the row whose ctx load is pending next.

// Conditionally load ctx row `idx` (skip if masked — its body is skipped too),
// then promote the pending mask. Scalar branch: mask is wave-uniform.
#define CLD(P, idx)                                                           \
    {                                                                         \
        if (__builtin_amdgcn_readfirstlane(P##n) == 0) {                      \
            const float* _np = cp + (size_t)(idx) * DD;                       \
            P##a = *reinterpret_cast<const float4*>(_np);                     \
            P##b = *reinterpret_cast<const float4*>(_np + 4);                 \
        }                                                                     \
        P##m = P##n;                                                          \
    }

// Prefetch mask for row `idx` (distance 6 ahead of the body).
#define MLD(P, idx) { P##n = mp[(idx)]; }

// Process the row in buffer P; whole body skipped for masked rows.
#define BODY(P)                                                               \
    {                                                                         \
        if (__builtin_amdgcn_readfirstlane(P##m) == 0) {                      \
            const float4 C0 = P##a, C1 = P##b;                                \
            float sa = C0.x * qa0.x, sb = C0.x * qb0.x;                       \
            sa = fmaf(C0.y, qa0.y, sa); sb = fmaf(C0.y, qb0.y, sb);           \
            sa = fmaf(C0.z, qa0.z, sa); sb = fmaf(C0.z, qb0.z, sb);           \
            sa = fmaf(C0.w, qa0.w, sa); sb = fmaf(C0.w, qb0.w, sb);           \
            sa = fmaf(C1.x, qa1.x, sa); sb = fmaf(C1.x, qb1.x, sb);           \
            sa = fmaf(C1.y, qa1.y, sa); sb = fmaf(C1.y, qb1.y, sb);           \
            sa = fmaf(C1.z, qa1.z, sa); sb = fmaf(C1.z, qb1.z, sb);           \
            sa = fmaf(C1.w, qa1.w, sa); sb = fmaf(C1.w, qb1.w, sb);           \
            sa = dpp_add<DPP_QUAD_XOR1>(sa); sb = dpp_add<DPP_QUAD_XOR1>(sb); \
            sa = dpp_add<DPP_QUAD_XOR2>(sa); sb = dpp_add<DPP_QUAD_XOR2>(sb); \
            sa = dpp_add<DPP_HALF_MIRR>(sa); sb = dpp_add<DPP_HALF_MIRR>(sb); \
            sa = dpp_add<DPP_ROW_MIRR>(sa);  sb = dpp_add<DPP_ROW_MIRR>(sb);  \
            const float pa = exp2f(sa);                                       \
            const float pb = exp2f(sb);                                       \
            den0 += pa; den1 += pb;                                           \
            A0.x = fmaf(pa, C0.x, A0.x); B0.x = fmaf(pb, C0.x, B0.x);         \
            A0.y = fmaf(pa, C0.y, A0.y); B0.y = fmaf(pb, C0.y, B0.y);         \
            A0.z = fmaf(pa, C0.z, A0.z); B0.z = fmaf(pb, C0.z, B0.z);         \
            A0.w = fmaf(pa, C0.w, A0.w); B0.w = fmaf(pb, C0.w, B0.w);         \
            A1.x = fmaf(pa, C1.x, A1.x); B1.x = fmaf(pb, C1.x, B1.x);         \
            A1.y = fmaf(pa, C1.y, A1.y); B1.y = fmaf(pb, C1.y, B1.y);         \
            A1.z = fmaf(pa, C1.z, A1.z); B1.z = fmaf(pb, C1.z, B1.z);         \
            A1.w = fmaf(pa, C1.w, A1.w); B1.w = fmaf(pb, C1.w, B1.w);         \
        }                                                                     \
    }

// ---------------- kernel 1: partial score+softmax-accumulate ----------------
// Block = (split s, batch b), 128 threads = 2 waves; wave = 4 groups of 16
// lanes; group g = head pair (2g,2g+1); lane j owns floats [j*8, j*8+8).
// 3 rotating single-row buffers; masked rows (~50%) skip BOTH the 55-instr
// body and the two float4 context loads (mask prefetched at distance 6).
// NO fence, NO atomics (R8 lesson: device-scope fences cost ~0.7 ms chip-wide).
__global__ __launch_bounds__(128, 4) void attn_partial_kernel(
    const float* __restrict__ context,   // [B][N][128]
    const int*   __restrict__ mask,      // [B][N]
    const float* __restrict__ qw,        // [B][8][128] (pre-scaled)
    float* __restrict__ part_acc,        // [B][NSLOT][8][128]
    float* __restrict__ part_den)        // [B][NSLOT][8]
{
    const int s = blockIdx.x;
    const int b = blockIdx.y;
    const int w = threadIdx.x >> 6;
    const int lane = threadIdx.x & 63;
    const int g = lane >> 4;     // head pair
    const int j = lane & 15;     // d-slice

    // qw slices for heads 2g, 2g+1 (16 regs)
    const float* qwb = qw + (size_t)b * NHEADS * DD + j * 8;
    const float4 qa0 = *reinterpret_cast<const float4*>(qwb + (2 * g) * DD);
    const float4 qa1 = *reinterpret_cast<const float4*>(qwb + (2 * g) * DD + 4);
    const float4 qb0 = *reinterpret_cast<const float4*>(qwb + (2 * g + 1) * DD);
    const float4 qb1 = *reinterpret_cast<const float4*>(qwb + (2 * g + 1) * DD + 4);

    float4 A0 = make_float4(0.f, 0.f, 0.f, 0.f), A1 = A0;  // acc head 2g
    float4 B0 = A0, B1 = A0;                                // acc head 2g+1
    float den0 = 0.f, den1 = 0.f;

    const int row0 = s * (2 * RPW) + w * RPW;
    const float* cp = context + ((size_t)b * NN + row0) * DD + j * 8;
    const int*   mp = mask + (size_t)b * NN + row0;

    // 3 rotating buffers (named locals; ctx loads in preamble unconditional)
    float4 p0a, p0b; int p0m, p0n;
    float4 p1a, p1b; int p1m, p1n;
    float4 p2a, p2b; int p2m, p2n;
    p0a = *reinterpret_cast<const float4*>(cp);
    p0b = *reinterpret_cast<const float4*>(cp + 4);
    p1a = *reinterpret_cast<const float4*>(cp + DD);
    p1b = *reinterpret_cast<const float4*>(cp + DD + 4);
    p2a = *reinterpret_cast<const float4*>(cp + 2 * DD);
    p2b = *reinterpret_cast<const float4*>(cp + 2 * DD + 4);
    p0m = mp[0]; p1m = mp[1]; p2m = mp[2];
    p0n = mp[3]; p1n = mp[4]; p2n = mp[5];

    // k = 0..41: 14 triple rounds; ctx prefetch +3 (<=44), mask prefetch +6 (<=47)
    for (int it = 0; it < 14; ++it) {
        const int k = 3 * it;
        BODY(p0) CLD(p0, k + 3) MLD(p0, k + 6)
        BODY(p1) CLD(p1, k + 4) MLD(p1, k + 7)
        BODY(p2) CLD(p2, k + 5) MLD(p2, k + 8)
    }
    // peeled tail: bodies 42..49
    BODY(p0) CLD(p0, 45) MLD(p0, 48)
    BODY(p1) CLD(p1, 46) MLD(p1, 49)
    BODY(p2) CLD(p2, 47)
    BODY(p0) CLD(p0, 48)
    BODY(p1) CLD(p1, 49)
    BODY(p2)            // row 47
    BODY(p0)            // row 48
    BODY(p1)            // row 49

    // ---- write this wave's partial slot (no LDS, no barrier) ----
    const int slot = s * 2 + w;
    float* pa_ = part_acc + (((size_t)b * NSLOT + slot) * NHEADS) * DD + j * 8;
    *reinterpret_cast<float4*>(pa_ + (2 * g) * DD)         = A0;
    *reinterpret_cast<float4*>(pa_ + (2 * g) * DD + 4)     = A1;
    *reinterpret_cast<float4*>(pa_ + (2 * g + 1) * DD)     = B0;
    *reinterpret_cast<float4*>(pa_ + (2 * g + 1) * DD + 4) = B1;
    if (j == 0) {
        float* pd = part_den + ((size_t)b * NSLOT + slot) * NHEADS;
        pd[2 * g]     = den0;
        pd[2 * g + 1] = den1;
    }
}

// ---------------- kernel 2: combine slots + Wv/Wfc projections --------------
__global__ __launch_bounds__(128) void attn_combine_kernel(
    const float* __restrict__ part_acc,  // [B][NSLOT][8][128]
    const float* __restrict__ part_den,  // [B][NSLOT][8]
    const float* __restrict__ Wv,        // [128][128]
    const float* __restrict__ Wfc,       // [128][128]
    float* __restrict__ out)             // [B][128]
{
    const int b = blockIdx.x;
    const int t = threadIdx.x;   // 128 threads

    __shared__ float s_dn[NHEADS];
    __shared__ float s_ca[NHEADS][132];
    __shared__ float s_o2[HH];

    if (t < NHEADS) {
        float dn = 0.f;
        #pragma unroll
        for (int sp = 0; sp < NSLOT; ++sp)
            dn += part_den[((size_t)b * NSLOT + sp) * NHEADS + t];
        s_dn[t] = dn;
    }
    __syncthreads();

    {
        const int d = t;
        #pragma unroll
        for (int h = 0; h < NHEADS; ++h) {
            float a = 0.f;
            #pragma unroll
            for (int sp = 0; sp < NSLOT; ++sp)
                a += part_acc[(((size_t)b * NSLOT + sp) * NHEADS + h) * DD + d];
            s_ca[h][d] = a / s_dn[h];
        }
    }
    __syncthreads();

    {
        const int h = t >> 4;
        const float* wvr = Wv + (size_t)t * DD;
        float a = 0.f;
        #pragma unroll 4
        for (int d = 0; d < DD; ++d) a = fmaf(s_ca[h][d], wvr[d], a);
        s_o2[t] = a;
    }
    __syncthreads();

    {
        const float* wfc = Wfc + (size_t)t * DD;
        float a = 0.f;
        #pragma unroll 4
        for (int k = 0; k < DD; ++k) a = fmaf(s_o2[k], wfc[k], a);
        out[(size_t)b * HH + t] = a;
    }
}

extern "C" void kernel_launch(void* const* d_in, const int* in_sizes, int n_in,
                              void* d_out, int out_size, void* d_ws, size_t ws_size,
                              hipStream_t stream) {
    const float* state_t = (const float*)d_in[0];
    const float* context = (const float*)d_in[1];
    const int*   mask    = (const int*)d_in[2];
    const float* Wq      = (const float*)d_in[3];
    const float* Wk      = (const float*)d_in[4];
    const float* Wv      = (const float*)d_in[5];
    const float* Wfc     = (const float*)d_in[6];
    float* out = (float*)d_out;

    float* qw       = (float*)d_ws;                                  // 2 MB
    float* part_acc = qw + (size_t)NB * NHEADS * DD;                 // 21 MB
    float* part_den = part_acc + (size_t)NB * NSLOT * NHEADS * DD;   // 0.3 MB

    qw_kernel<<<dim3(NB), dim3(256), 0, stream>>>(state_t, Wq, Wk, qw);
    attn_partial_kernel<<<dim3(NSPLIT, NB), dim3(128), 0, stream>>>(
        context, mask, qw, part_acc, part_den);
    attn_combine_kernel<<<dim3(NB), dim3(128), 0, stream>>>(
        part_acc, part_den, Wv, Wfc, out);
}

// Round 12
// 99.593 us; speedup vs baseline: 2.4808x; 1.0395x over previous
//
#include <hip/hip_runtime.h>

#define NHEADS 8
#define NB 512
#define NN 1000
#define DD 128
#define HH 128
#define SDIM 384              // D*CAT
#define NSPLIT 10             // blocks per batch
#define NSLOT (NSPLIT * 2)    // one partial slot per wave
#define RPW 50                // rows per wave

// DPP helper: x += lane-permuted x. Pure VALU, no DS pipe.
template <int CTRL>
__device__ __forceinline__ float dpp_add(float x) {
    int y = __builtin_amdgcn_update_dpp(0, __float_as_int(x), CTRL, 0xf, 0xf, true);
    return x + __int_as_float(y);
}
#define DPP_QUAD_XOR1 0xB1   // quad_perm(1,0,3,2)
#define DPP_QUAD_XOR2 0x4E   // quad_perm(2,3,0,1)
#define DPP_HALF_MIRR 0x141  // mirror within 8
#define DPP_ROW_MIRR  0x140  // mirror within 16

// ---------------- kernel 0: per-batch qw precompute (coalesced) -------------
__global__ __launch_bounds__(256) void qw_kernel(
    const float* __restrict__ state_t,   // [B][384]
    const float* __restrict__ Wq,        // [128][384]
    const float* __restrict__ Wk,        // [128][128]
    float* __restrict__ qw)              // [B][8][128]
{
    const int b = blockIdx.x;
    const int t = threadIdx.x;
    const int lane = t & 63;
    const int w = t >> 6;

    __shared__ float s_q[HH];

    float st[6];
    #pragma unroll
    for (int j = 0; j < 6; ++j) st[j] = state_t[(size_t)b * SDIM + j * 64 + lane];

    for (int it = 0; it < 16; ++it) {
        const int r0 = w * 32 + it * 2;
        const float* w0 = Wq + (size_t)r0 * SDIM;
        const float* w1 = w0 + SDIM;
        float p0 = 0.f, p1 = 0.f;
        #pragma unroll
        for (int j = 0; j < 6; ++j) {
            p0 = fmaf(w0[j * 64 + lane], st[j], p0);
            p1 = fmaf(w1[j * 64 + lane], st[j], p1);
        }
        #pragma unroll
        for (int off = 32; off >= 1; off >>= 1) {
            p0 += __shfl_xor(p0, off, 64);
            p1 += __shfl_xor(p1, off, 64);
        }
        if (lane == 0) { s_q[r0] = p0; s_q[r0 + 1] = p1; }
    }
    __syncthreads();

    {
        const int d  = t & 127;
        const int h0 = (t >> 7) * 4;
        const float sc = 0.0625f * 1.4426950408889634f;  // (1/hd) * log2(e)
        for (int hh = 0; hh < 4; ++hh) {
            const int h = h0 + hh;
            float a = 0.f;
            #pragma unroll
            for (int j = 0; j < 16; ++j)
                a = fmaf(s_q[h * 16 + j], Wk[(size_t)(h * 16 + j) * DD + d], a);
            qw[(size_t)b * NHEADS * DD + h * DD + d] = a * sc;
        }
    }
}

// Wave-uniform mask for row k of this wave: one SALU readlane from the
// lane-distributed mask vector mv (loaded once; no in-loop mask memory ops).
#define MSK(kidx) (__builtin_amdgcn_readlane(mv, (kidx)))

// Conditionally load ctx row `idx` into buffer P (skipped if row masked —
// its body is skipped under the same condition, so values never used).
#define CLD(P, idx)                                                           \
    {                                                                         \
        if (MSK(idx) == 0) {                                                  \
            const float* _np = cp + (size_t)(idx) * DD;                       \
            P##a = *reinterpret_cast<const float4*>(_np);                     \
            P##b = *reinterpret_cast<const float4*>(_np + 4);                 \
        }                                                                     \
    }

// Process row `idx` held in buffer P; whole body skipped for masked rows.
#define BODY(P, idx)                                                          \
    {                                                                         \
        if (MSK(idx) == 0) {                                                  \
            const float4 C0 = P##a, C1 = P##b;                                \
            float sa = C0.x * qa0.x, sb = C0.x * qb0.x;                       \
            sa = fmaf(C0.y, qa0.y, sa); sb = fmaf(C0.y, qb0.y, sb);           \
            sa = fmaf(C0.z, qa0.z, sa); sb = fmaf(C0.z, qb0.z, sb);           \
            sa = fmaf(C0.w, qa0.w, sa); sb = fmaf(C0.w, qb0.w, sb);           \
            sa = fmaf(C1.x, qa1.x, sa); sb = fmaf(C1.x, qb1.x, sb);           \
            sa = fmaf(C1.y, qa1.y, sa); sb = fmaf(C1.y, qb1.y, sb);           \
            sa = fmaf(C1.z, qa1.z, sa); sb = fmaf(C1.z, qb1.z, sb);           \
            sa = fmaf(C1.w, qa1.w, sa); sb = fmaf(C1.w, qb1.w, sb);           \
            sa = dpp_add<DPP_QUAD_XOR1>(sa); sb = dpp_add<DPP_QUAD_XOR1>(sb); \
            sa = dpp_add<DPP_QUAD_XOR2>(sa); sb = dpp_add<DPP_QUAD_XOR2>(sb); \
            sa = dpp_add<DPP_HALF_MIRR>(sa); sb = dpp_add<DPP_HALF_MIRR>(sb); \
            sa = dpp_add<DPP_ROW_MIRR>(sa);  sb = dpp_add<DPP_ROW_MIRR>(sb);  \
            const float pa = exp2f(sa);                                       \
            const float pb = exp2f(sb);                                       \
            den0 += pa; den1 += pb;                                           \
            A0.x = fmaf(pa, C0.x, A0.x); B0.x = fmaf(pb, C0.x, B0.x);         \
            A0.y = fmaf(pa, C0.y, A0.y); B0.y = fmaf(pb, C0.y, B0.y);         \
            A0.z = fmaf(pa, C0.z, A0.z); B0.z = fmaf(pb, C0.z, B0.z);         \
            A0.w = fmaf(pa, C0.w, A0.w); B0.w = fmaf(pb, C0.w, B0.w);         \
            A1.x = fmaf(pa, C1.x, A1.x); B1.x = fmaf(pb, C1.x, B1.x);         \
            A1.y = fmaf(pa, C1.y, A1.y); B1.y = fmaf(pb, C1.y, B1.y);         \
            A1.z = fmaf(pa, C1.z, A1.z); B1.z = fmaf(pb, C1.z, B1.z);         \
            A1.w = fmaf(pa, C1.w, A1.w); B1.w = fmaf(pb, C1.w, B1.w);         \
        }                                                                     \
    }

// ---------------- kernel 1: partial score+softmax-accumulate ----------------
// Block = (split s, batch b), 128 threads = 2 waves; wave = 4 groups of 16
// lanes; group g = head pair (2g,2g+1); lane j owns floats [j*8, j*8+8).
// All 50 row-masks arrive in ONE lane-distributed load (mv); per-row mask is
// a SALU readlane -> no in-loop mask loads, no branch-to-load latency
// coupling. Masked rows (~50%) skip body AND ctx loads. 3 rotating buffers.
// NO fence, NO atomics (R8 lesson: device fences ~0.7 ms chip-wide).
__global__ __launch_bounds__(128, 4) void attn_partial_kernel(
    const float* __restrict__ context,   // [B][N][128]
    const int*   __restrict__ mask,      // [B][N]
    const float* __restrict__ qw,        // [B][8][128] (pre-scaled)
    float* __restrict__ part_acc,        // [B][NSLOT][8][128]
    float* __restrict__ part_den)        // [B][NSLOT][8]
{
    const int s = blockIdx.x;
    const int b = blockIdx.y;
    const int w = threadIdx.x >> 6;
    const int lane = threadIdx.x & 63;
    const int g = lane >> 4;     // head pair
    const int j = lane & 15;     // d-slice

    const int row0 = s * (2 * RPW) + w * RPW;
    const float* cp = context + ((size_t)b * NN + row0) * DD + j * 8;
    const int*   mp = mask + (size_t)b * NN + row0;

    // one load: lane i holds mask of row i (lanes >= RPW clamp to row RPW-1)
    const int mv = mp[lane < RPW ? lane : RPW - 1];

    // qw slices for heads 2g, 2g+1 (16 regs)
    const float* qwb = qw + (size_t)b * NHEADS * DD + j * 8;
    const float4 qa0 = *reinterpret_cast<const float4*>(qwb + (2 * g) * DD);
    const float4 qa1 = *reinterpret_cast<const float4*>(qwb + (2 * g) * DD + 4);
    const float4 qb0 = *reinterpret_cast<const float4*>(qwb + (2 * g + 1) * DD);
    const float4 qb1 = *reinterpret_cast<const float4*>(qwb + (2 * g + 1) * DD + 4);

    float4 A0 = make_float4(0.f, 0.f, 0.f, 0.f), A1 = A0;  // acc head 2g
    float4 B0 = A0, B1 = A0;                                // acc head 2g+1
    float den0 = 0.f, den1 = 0.f;

    // 3 rotating single-row buffers (named locals)
    float4 p0a, p0b;
    float4 p1a, p1b;
    float4 p2a, p2b;
    CLD(p0, 0)
    CLD(p1, 1)
    CLD(p2, 2)

    // rows 0..44: 15 triple rounds; ctx prefetch +3 (max 47)
    #pragma unroll
    for (int it = 0; it < 15; ++it) {
        const int k = 3 * it;
        BODY(p0, k)     CLD(p0, k + 3)
        BODY(p1, k + 1) CLD(p1, k + 4)
        BODY(p2, k + 2) CLD(p2, k + 5)
    }
    // peeled tail: rows 45..49
    BODY(p0, 45) CLD(p0, 48)
    BODY(p1, 46) CLD(p1, 49)
    BODY(p2, 47)
    BODY(p0, 48)
    BODY(p1, 49)

    // ---- write this wave's partial slot (no LDS, no barrier) ----
    const int slot = s * 2 + w;
    float* pa_ = part_acc + (((size_t)b * NSLOT + slot) * NHEADS) * DD + j * 8;
    *reinterpret_cast<float4*>(pa_ + (2 * g) * DD)         = A0;
    *reinterpret_cast<float4*>(pa_ + (2 * g) * DD + 4)     = A1;
    *reinterpret_cast<float4*>(pa_ + (2 * g + 1) * DD)     = B0;
    *reinterpret_cast<float4*>(pa_ + (2 * g + 1) * DD + 4) = B1;
    if (j == 0) {
        float* pd = part_den + ((size_t)b * NSLOT + slot) * NHEADS;
        pd[2 * g]     = den0;
        pd[2 * g + 1] = den1;
    }
}

// ---------------- kernel 2: combine slots + Wv/Wfc projections --------------
__global__ __launch_bounds__(128) void attn_combine_kernel(
    const float* __restrict__ part_acc,  // [B][NSLOT][8][128]
    const float* __restrict__ part_den,  // [B][NSLOT][8]
    const float* __restrict__ Wv,        // [128][128]
    const float* __restrict__ Wfc,       // [128][128]
    float* __restrict__ out)             // [B][128]
{
    const int b = blockIdx.x;
    const int t = threadIdx.x;   // 128 threads

    __shared__ float s_dn[NHEADS];
    __shared__ float s_ca[NHEADS][132];
    __shared__ float s_o2[HH];

    if (t < NHEADS) {
        float dn = 0.f;
        #pragma unroll
        for (int sp = 0; sp < NSLOT; ++sp)
            dn += part_den[((size_t)b * NSLOT + sp) * NHEADS + t];
        s_dn[t] = dn;
    }
    __syncthreads();

    {
        const int d = t;
        #pragma unroll
        for (int h = 0; h < NHEADS; ++h) {
            float a = 0.f;
            #pragma unroll
            for (int sp = 0; sp < NSLOT; ++sp)
                a += part_acc[(((size_t)b * NSLOT + sp) * NHEADS + h) * DD + d];
            s_ca[h][d] = a / s_dn[h];
        }
    }
    __syncthreads();

    {
        const int h = t >> 4;
        const float* wvr = Wv + (size_t)t * DD;
        float a = 0.f;
        #pragma unroll 4
        for (int d = 0; d < DD; ++d) a = fmaf(s_ca[h][d], wvr[d], a);
        s_o2[t] = a;
    }
    __syncthreads();

    {
        const float* wfc = Wfc + (size_t)t * DD;
        float a = 0.f;
        #pragma unroll 4
        for (int k = 0; k < DD; ++k) a = fmaf(s_o2[k], wfc[k], a);
        out[(size_t)b * HH + t] = a;
    }
}

extern "C" void kernel_launch(void* const* d_in, const int* in_sizes, int n_in,
                              void* d_out, int out_size, void* d_ws, size_t ws_size,
                              hipStream_t stream) {
    const float* state_t = (const float*)d_in[0];
    const float* context = (const float*)d_in[1];
    const int*   mask    = (const int*)d_in[2];
    const float* Wq      = (const float*)d_in[3];
    const float* Wk      = (const float*)d_in[4];
    const float* Wv      = (const float*)d_in[5];
    const float* Wfc     = (const float*)d_in[6];
    float* out = (float*)d_out;

    float* qw       = (float*)d_ws;                                  // 2 MB
    float* part_acc = qw + (size_t)NB * NHEADS * DD;                 // 21 MB
    float* part_den = part_acc + (size_t)NB * NSLOT * NHEADS * DD;   // 0.3 MB

    qw_kernel<<<dim3(NB), dim3(256), 0, stream>>>(state_t, Wq, Wk, qw);
    attn_partial_kernel<<<dim3(NSPLIT, NB), dim3(128), 0, stream>>>(
        context, mask, qw, part_acc, part_den);
    attn_combine_kernel<<<dim3(NB), dim3(128), 0, stream>>>(
        part_acc, part_den, Wv, Wfc, out);
}